// Round 12
// baseline (217.608 us; speedup 1.0000x reference)
//
#include <hip/hip_runtime.h>
#include <hip/hip_bf16.h>
#include <cstdint>

typedef __hip_bfloat16 bf16;
typedef __attribute__((ext_vector_type(8))) short short8;
typedef __attribute__((ext_vector_type(4))) short short4v;
typedef __attribute__((ext_vector_type(4))) float f32x4;
typedef __attribute__((ext_vector_type(2))) unsigned int uint2v;

__device__ __forceinline__ float bf2f(bf16 v) { return __bfloat162float(v); }
__device__ __forceinline__ bf16  f2bf(float v) { return __float2bfloat16(v); }
__device__ __forceinline__ float rbf(short s) {
  union { uint32_t u; float f; } c; c.u = ((uint32_t)(uint16_t)s) << 16; return c.f;
}
__device__ __forceinline__ uint32_t pack2(float a, float b) {
  bf16 x = f2bf(a), y = f2bf(b);
  return (uint32_t)(*(uint16_t*)&x) | ((uint32_t)(*(uint16_t*)&y) << 16);
}
__device__ __forceinline__ uint2v pack4(float a, float b, float c, float d) {
  uint2v r; r[0] = pack2(a, b); r[1] = pack2(c, d); return r;
}
// granule swizzle: XOR low-3 bits of 8-elem granule index with row&7
__device__ __forceinline__ int swz(int row, int g) { return g ^ (row & 7); }

// window-order row m -> token index (t*4096 + p)
__device__ __forceinline__ int win_to_token(int m) {
  int n = m >> 8, l = m & 255;
  int t = n >> 4, win = n & 15;
  int wi = win >> 2, wj = win & 3;
  int u = l >> 4, v = l & 15;
  return (t << 12) | ((wi * 16 + u) << 6) | (wj * 16 + v);
}

// ---------------- merged: weight packing + selector MLP ----------------
__global__ __launch_bounds__(256) void k_packsel(
    const float* __restrict__ qkvw, const float* __restrict__ projw,
    const float* __restrict__ mlp1w, const float* __restrict__ mlp2w,
    const float* __restrict__ upw, const float* __restrict__ qkvb,
    bf16* __restrict__ Bt_qkv, bf16* __restrict__ Bt_proj,
    bf16* __restrict__ Bt_mlp1, bf16* __restrict__ Bt_mlp2,
    bf16* __restrict__ Bt_up, float* __restrict__ biasq,
    const float* __restrict__ x, const float* __restrict__ gu,
    const float* __restrict__ s1w, const float* __restrict__ s1b,
    const float* __restrict__ s2w, const float* __restrict__ s2b,
    const float* __restrict__ s3w, const float* __restrict__ s3b,
    float* __restrict__ f1o, float* __restrict__ f2o, float* __restrict__ f3o,
    float* __restrict__ maskp) {
  if (blockIdx.x < 1203) {
    int idx = blockIdx.x * 256 + threadIdx.x;
    const int e0 = 576 * 192, e1 = e0 + 192 * 192, e2 = e1 + 384 * 192,
              e3 = e2 + 192 * 384, e4 = e3 + 64 * 192, e5 = e4 + 576;
    if (idx < e0) {
      int np = idx / 192, k = idx % 192;
      int buf = np / 192, colp = np % 192;
      int hd = colp >> 5, dd = colp & 31;
      float v = 0.f;
      if (dd < 30 && k < 180) v = qkvw[(size_t)k * 540 + buf * 180 + hd * 30 + dd];
      Bt_qkv[idx] = f2bf(v);
    } else if (idx < e1) {
      int off = idx - e0; int n = off / 192, kp = off % 192;
      int hd = kp >> 5, dd = kp & 31;
      float v = (dd < 30 && n < 180) ? projw[(size_t)(hd * 30 + dd) * 180 + n] : 0.f;
      Bt_proj[off] = f2bf(v);
    } else if (idx < e2) {
      int off = idx - e1; int n = off / 192, k = off % 192;
      Bt_mlp1[off] = f2bf((k < 180 && n < 360) ? mlp1w[(size_t)k * 360 + n] : 0.f);
    } else if (idx < e3) {
      int off = idx - e2; int n = off / 384, k = off % 384;
      Bt_mlp2[off] = f2bf((k < 360 && n < 180) ? mlp2w[(size_t)k * 180 + n] : 0.f);
    } else if (idx < e4) {
      int off = idx - e3; int n = off / 192, k = off % 192;
      Bt_up[off] = f2bf((k < 180 && n < 48) ? upw[(size_t)k * 48 + n] : 0.f);
    } else if (idx < e5) {
      int np = idx - e4;
      int buf = np / 192, colp = np % 192;
      int hd = colp >> 5, dd = colp & 31;
      biasq[np] = (dd < 30) ? qkvb[buf * 180 + hd * 30 + dd] : 0.f;
    }
    return;
  }
  // ---- selector (blocks 1203..1218), 256 threads ----
  int t = blockIdx.x - 1203;
  int tid = threadIdx.x;
  int th = t >> 2, tw = t & 3;
  __shared__ float pooled[192];
  __shared__ float red[256];
  __shared__ float f1s[64], f2s[32], f3s[2];
  if (tid < 192) {
    int ch = tid % 3, j = (tid / 3) & 7, i = tid / 24;
    const float* xp = x + ch * 65536 + (th * 64 + i * 8) * 256 + (tw * 64 + j * 8);
    float s = 0.f;
#pragma unroll
    for (int a = 0; a < 8; ++a)
#pragma unroll
      for (int b = 0; b < 8; ++b) s += xp[a * 256 + b];
    pooled[tid] = s * (1.0f / 64.0f);
  }
  __syncthreads();
  {
    int o = tid & 63, part = tid >> 6;
    float s = 0.f;
    for (int k = part * 48; k < part * 48 + 48; ++k) s = fmaf(pooled[k], s1w[k * 64 + o], s);
    red[tid] = s;
  }
  __syncthreads();
  if (tid < 64) {
    float v = red[tid] + red[tid + 64] + red[tid + 128] + red[tid + 192] + s1b[tid];
    f1o[t * 64 + tid] = v;
    f1s[tid] = fmaxf(v, 0.f);
  }
  __syncthreads();
  {
    int o = tid & 31, part = tid >> 5;
    float s = 0.f;
    for (int k = part * 8; k < part * 8 + 8; ++k) s = fmaf(f1s[k], s2w[k * 32 + o], s);
    red[tid] = s;
  }
  __syncthreads();
  if (tid < 32) {
    float v = s2b[tid];
#pragma unroll
    for (int p = 0; p < 8; ++p) v += red[tid + p * 32];
    f2o[t * 32 + tid] = v;
    f2s[tid] = fmaxf(v, 0.f);
  }
  __syncthreads();
  if (tid < 2) {
    float s = s3b[tid];
    for (int k = 0; k < 32; ++k) s = fmaf(f2s[k], s3w[k * 2 + tid], s);
    f3o[t * 2 + tid] = s;
    f3s[tid] = s;
  }
  __syncthreads();
  if (tid == 0) {
    float g0 = -logf(-logf(gu[t * 2 + 0] + 1e-10f) + 1e-10f);
    float g1 = -logf(-logf(gu[t * 2 + 1] + 1e-10f) + 1e-10f);
    maskp[t] = (f3s[1] + g1 > f3s[0] + g0) ? 1.0f : 0.0f;
  }
}

// ---------------- embed (3->180) + LN1 applied, outputs window-major ----------------
__global__ __launch_bounds__(256) void k_embed(
    const float* __restrict__ x, const float* __restrict__ ew,
    const float* __restrict__ eb, const float* __restrict__ g1,
    const float* __restrict__ b1, bf16* __restrict__ tok,
    bf16* __restrict__ Aq) {
  int wrow = blockIdx.x * 4 + (threadIdx.x >> 6);
  int lane = threadIdx.x & 63;
  int token = win_to_token(wrow);
  int t = token >> 12, p = token & 4095;
  int r = p >> 6, c = p & 63;
  int gh = (t >> 2) * 64 + r, gw = (t & 3) * 64 + c;
  float x0 = x[gh * 256 + gw];
  float x1 = x[65536 + gh * 256 + gw];
  float x2 = x[131072 + gh * 256 + gw];
  float v[3];
  float s = 0.f, s2 = 0.f;
#pragma unroll
  for (int i = 0; i < 3; ++i) {
    int e = lane + i * 64;
    float vv = 0.f;
    if (e < 180) {
      vv = eb[e];
      vv = fmaf(x0, ew[e], vv);
      vv = fmaf(x1, ew[180 + e], vv);
      vv = fmaf(x2, ew[360 + e], vv);
      tok[(size_t)wrow * 180 + e] = f2bf(vv);
      s += vv; s2 = fmaf(vv, vv, s2);
    }
    v[i] = vv;
  }
#pragma unroll
  for (int off = 32; off; off >>= 1) { s += __shfl_xor(s, off); s2 += __shfl_xor(s2, off); }
  float mu = s * (1.f / 180.f);
  float rs = rsqrtf(s2 * (1.f / 180.f) - mu * mu + 1e-5f);
#pragma unroll
  for (int i = 0; i < 3; ++i) {
    int e = lane + i * 64;
    if (e < 192) {
      float a = (e < 180) ? ((v[i] - mu) * rs * g1[e] + b1[e]) : 0.f;
      Aq[(size_t)wrow * 192 + e] = f2bf(a);
    }
  }
}

// ---------------- qkv GEMM: 1024 thr / 256 rows / grid 256; dbuf LDS B ------
__global__ __launch_bounds__(1024, 1) void k_qkv3(
    const bf16* __restrict__ A, const bf16* __restrict__ Bt,
    const float* __restrict__ biasq, bf16* __restrict__ Qp,
    bf16* __restrict__ Kp, bf16* __restrict__ Vp) {
  __shared__ bf16 Bs[2][64 * 192];
  const int tid = threadIdx.x;
  const int w = tid >> 6, l = tid & 63;
  const int lr = l & 15, lk = l >> 4;
  const int row = blockIdx.x * 256 + w * 16 + lr;

  short8 fa[6];
  {
    const bf16* Ab = A + (size_t)row * 192 + lk * 8;
#pragma unroll
    for (int ks = 0; ks < 6; ++ks) fa[ks] = *(const short8*)(Ab + ks * 32);
  }

  for (int c = tid; c < 1536; c += 1024) {
    int n = c / 24, g = c % 24;
    *(short8*)&Bs[0][n * 192 + swz(n, g) * 8] = *(const short8*)(Bt + (size_t)n * 192 + g * 8);
  }

  for (int nt = 0; nt < 9; ++nt) {
    __syncthreads();
    if (nt < 8) {
      const bf16* src = Bt + (size_t)(nt + 1) * 64 * 192;
      bf16* dstb = Bs[(nt + 1) & 1];
      for (int c = tid; c < 1536; c += 1024) {
        int n = c / 24, g = c % 24;
        *(short8*)&dstb[n * 192 + swz(n, g) * 8] = *(const short8*)(src + (size_t)n * 192 + g * 8);
      }
    }
    const bf16* Bb = Bs[nt & 1];
    f32x4 acc[4];
#pragma unroll
    for (int j = 0; j < 4; ++j) acc[j] = (f32x4){0.f, 0.f, 0.f, 0.f};
#pragma unroll
    for (int ks = 0; ks < 6; ++ks) {
      short8 fb[4];
#pragma unroll
      for (int j = 0; j < 4; ++j) {
        int rn = j * 16 + lr;
        fb[j] = *(const short8*)&Bb[rn * 192 + swz(rn, ks * 4 + lk) * 8];
      }
#pragma unroll
      for (int j = 0; j < 4; ++j)
        acc[j] = __builtin_amdgcn_mfma_f32_16x16x32_bf16(fb[j], fa[ks], acc[j], 0, 0, 0);
    }
    bf16* dst = (nt < 3) ? Qp : (nt < 6) ? Kp : Vp;
    int c0 = (nt % 3) * 64;
#pragma unroll
    for (int j = 0; j < 4; ++j) {
      int np = nt * 64 + j * 16 + lk * 4;
      f32x4 bv = *(const f32x4*)&biasq[np];
      *(uint2v*)(dst + (size_t)row * 192 + c0 + j * 16 + lk * 4) =
          pack4(acc[j][0] + bv[0], acc[j][1] + bv[1], acc[j][2] + bv[2], acc[j][3] + bv[3]);
    }
  }
}

// ---------------- MFMA attention: block = (window, head), swapped PV ----------------
__global__ __launch_bounds__(256) void k_attn2(
    const bf16* __restrict__ Qp, const bf16* __restrict__ Kp,
    const bf16* __restrict__ Vp, bf16* __restrict__ av) {
  const int blk = blockIdx.x;
  const int win = blk / 6, hd = blk % 6;
  const int tid = threadIdx.x;
  const int w = tid >> 6, l = tid & 63;
  const int lr = l & 15, lk = l >> 4;
  const float scale = 0.18257418583505536f;  // 1/sqrt(30)

  __shared__ bf16 Ks[256][40];
  __shared__ bf16 Vs[32][264];
  __shared__ bf16 Ps[4][16][264];

  {  // stage K rows
    const bf16* src = Kp + (size_t)(win * 256 + tid) * 192 + hd * 32;
#pragma unroll
    for (int c = 0; c < 4; ++c)
      *(short8*)&Ks[tid][c * 8] = *(const short8*)(src + c * 8);
  }
  {  // stage V rows -> transposed Vs[d][key]
    const bf16* src = Vp + (size_t)(win * 256 + tid) * 192 + hd * 32;
    short8 vv[4];
#pragma unroll
    for (int c = 0; c < 4; ++c) vv[c] = *(const short8*)(src + c * 8);
#pragma unroll
    for (int c = 0; c < 4; ++c)
#pragma unroll
      for (int e = 0; e < 8; ++e)
        *(short*)&Vs[c * 8 + e][tid] = vv[c][e];
  }
  __syncthreads();

  for (int qt = 0; qt < 4; ++qt) {
    const int qbase = qt * 64 + w * 16;
    short8 fq = *(const short8*)(Qp + (size_t)(win * 256 + qbase + lr) * 192 + hd * 32 + lk * 8);
    f32x4 accS[16];
#pragma unroll
    for (int kt = 0; kt < 16; ++kt) {
      short8 fk = *(const short8*)(&Ks[kt * 16 + lr][lk * 8]);
      accS[kt] = __builtin_amdgcn_mfma_f32_16x16x32_bf16(
          fk, fq, (f32x4){0.f, 0.f, 0.f, 0.f}, 0, 0, 0);
    }
    float mraw = -1e30f;
#pragma unroll
    for (int kt = 0; kt < 16; ++kt)
#pragma unroll
      for (int r = 0; r < 4; ++r) mraw = fmaxf(mraw, accS[kt][r]);
    mraw = fmaxf(mraw, __shfl_xor(mraw, 16));
    mraw = fmaxf(mraw, __shfl_xor(mraw, 32));
    const float mc = mraw * scale;
    float lsum = 0.f;
#pragma unroll
    for (int kt = 0; kt < 16; ++kt) {
      float p0 = __expf(fmaf(accS[kt][0], scale, -mc));
      float p1 = __expf(fmaf(accS[kt][1], scale, -mc));
      float p2 = __expf(fmaf(accS[kt][2], scale, -mc));
      float p3 = __expf(fmaf(accS[kt][3], scale, -mc));
      lsum += (p0 + p1) + (p2 + p3);
      *(uint32_t*)&Ps[w][lr][kt * 16 + lk * 4]     = pack2(p0, p1);
      *(uint32_t*)&Ps[w][lr][kt * 16 + lk * 4 + 2] = pack2(p2, p3);
    }
    lsum += __shfl_xor(lsum, 16);
    lsum += __shfl_xor(lsum, 32);
    __syncthreads();
    f32x4 accO0 = (f32x4){0.f, 0.f, 0.f, 0.f};
    f32x4 accO1 = (f32x4){0.f, 0.f, 0.f, 0.f};
#pragma unroll
    for (int ks = 0; ks < 8; ++ks) {
      short8 fp  = *(const short8*)(&Ps[w][lr][ks * 32 + lk * 8]);
      short8 fv0 = *(const short8*)(&Vs[lr][ks * 32 + lk * 8]);
      short8 fv1 = *(const short8*)(&Vs[16 + lr][ks * 32 + lk * 8]);
      accO0 = __builtin_amdgcn_mfma_f32_16x16x32_bf16(fv0, fp, accO0, 0, 0, 0);
      accO1 = __builtin_amdgcn_mfma_f32_16x16x32_bf16(fv1, fp, accO1, 0, 0, 0);
    }
    float invl = 1.f / lsum;
    bf16* avrow = av + (size_t)(win * 256 + qbase + lr) * 192 + hd * 32;
    *(uint2v*)(avrow + lk * 4) =
        pack4(accO0[0] * invl, accO0[1] * invl, accO0[2] * invl, accO0[3] * invl);
    *(uint2v*)(avrow + 16 + lk * 4) =
        pack4(accO1[0] * invl, accO1[1] * invl, accO1[2] * invl, accO1[3] * invl);
    __syncthreads();
  }
}

// ---------------- fused post-attn, 1024 thr / 256 rows / grid 256 ----
// 16-tile double-buffered weight stream; Hm (96KB) holds H2 -> mid slab -> tok3.
__global__ __launch_bounds__(1024, 1) void k_post(
    const bf16* __restrict__ av, const bf16* __restrict__ tok,
    const bf16* __restrict__ Btp, const float* __restrict__ pb,
    const float* __restrict__ g2, const float* __restrict__ b2,
    const bf16* __restrict__ Bt1, const float* __restrict__ b1m,
    const bf16* __restrict__ Bt2, const float* __restrict__ b2m,
    const bf16* __restrict__ Btu, const float* __restrict__ bu,
    bf16* __restrict__ up) {
  __shared__ bf16 Bs[2][64 * 192];   // 49,152 B
  __shared__ bf16 Hm[256 * 192];     // 98,304 B
  const int tid = threadIdx.x;
  const int w = tid >> 6, l = tid & 63;
  const int lr = l & 15, lk = l >> 4;
  const int row_l = w * 16 + lr;
  const int row_g = blockIdx.x * 256 + row_l;
  const int half = (lk & 1) * 4;

#define STAGE_A(srcp, dstb)                                               \
  {                                                                       \
    const bf16* _s = (srcp);                                              \
    bf16* _d = (dstb);                                                    \
    for (int c = tid; c < 1536; c += 1024) {                              \
      int n = c / 24, g = c % 24;                                         \
      *(short8*)&_d[n * 192 + swz(n, g) * 8] =                            \
          *(const short8*)(_s + (size_t)n * 192 + g * 8);                 \
    }                                                                     \
  }
#define STAGE_S(ntv, dstb)                                                \
  {                                                                       \
    bf16* _d = (dstb);                                                    \
    for (int c = tid; c < 1536; c += 1024) {                              \
      int n = c / 8, g = c % 8;                                           \
      *(short8*)&_d[n * 64 + swz(n, g) * 8] =                             \
          *(const short8*)(Bt2 + (size_t)n * 384 + (ntv) * 64 + g * 8);   \
    }                                                                     \
  }

  // av A-frags
  short8 fa[6];
  {
    const bf16* ab = av + (size_t)row_g * 192 + lk * 8;
#pragma unroll
    for (int ks = 0; ks < 6; ++ks) fa[ks] = *(const short8*)(ab + ks * 32);
  }

  f32x4 t2v[3][4];

  // ---- prologue: stage proj0 ----
  STAGE_A(Btp, Bs[0]);

  // ======= proj tiles (t=0,1,2) =======
#pragma unroll
  for (int nt = 0; nt < 3; ++nt) {
    __syncthreads();
    if (nt < 2) { STAGE_A(Btp + (size_t)(nt + 1) * 64 * 192, Bs[(nt + 1) & 1]); }
    else        { STAGE_A(Bt1, Bs[1]); }  // tile 3 = mlp1_0
    const bf16* Bb = Bs[nt & 1];
    f32x4 acc[4];
#pragma unroll
    for (int j = 0; j < 4; ++j) acc[j] = (f32x4){0.f, 0.f, 0.f, 0.f};
#pragma unroll
    for (int ks = 0; ks < 6; ++ks) {
      short8 fb[4];
#pragma unroll
      for (int j = 0; j < 4; ++j) {
        int rn = j * 16 + lr;
        fb[j] = *(const short8*)&Bb[rn * 192 + swz(rn, ks * 4 + lk) * 8];
      }
#pragma unroll
      for (int j = 0; j < 4; ++j)
        acc[j] = __builtin_amdgcn_mfma_f32_16x16x32_bf16(fb[j], fa[ks], acc[j], 0, 0, 0);
    }
#pragma unroll
    for (int j = 0; j < 4; ++j) {
      int n = nt * 64 + j * 16 + lk * 4;
      if (n < 180) {
        f32x4 bv = *(const f32x4*)&pb[n];
        short4v tv = *(const short4v*)(tok + (size_t)row_g * 180 + n);
#pragma unroll
        for (int q = 0; q < 4; ++q) t2v[nt][j][q] = acc[j][q] + bv[q] + rbf(tv[q]);
      } else {
        t2v[nt][j] = (f32x4){0.f, 0.f, 0.f, 0.f};
      }
    }
  }

  // ======= LN2 stats from regs, H2 -> Hm =======
  {
    float s = 0.f, s2 = 0.f;
#pragma unroll
    for (int nt = 0; nt < 3; ++nt)
#pragma unroll
      for (int j = 0; j < 4; ++j)
#pragma unroll
        for (int q = 0; q < 4; ++q) { float v = t2v[nt][j][q]; s += v; s2 = fmaf(v, v, s2); }
    s += __shfl_xor(s, 16);  s += __shfl_xor(s, 32);
    s2 += __shfl_xor(s2, 16); s2 += __shfl_xor(s2, 32);
    float mu = s * (1.f / 180.f);
    float rs = rsqrtf(s2 * (1.f / 180.f) - mu * mu + 1e-5f);
#pragma unroll
    for (int nt = 0; nt < 3; ++nt)
#pragma unroll
      for (int j = 0; j < 4; ++j) {
        int n = nt * 64 + j * 16 + lk * 4;
        float h[4] = {0.f, 0.f, 0.f, 0.f};
        if (n < 180) {
          f32x4 gv = *(const f32x4*)&g2[n];
          f32x4 bv = *(const f32x4*)&b2[n];
#pragma unroll
          for (int q = 0; q < 4; ++q) h[q] = (t2v[nt][j][q] - mu) * rs * gv[q] + bv[q];
        }
        int g = nt * 8 + j * 2 + (lk >> 1);
        *(uint2v*)&Hm[row_l * 192 + swz(row_l, g) * 8 + half] = pack4(h[0], h[1], h[2], h[3]);
      }
  }

  short8 fh[6];
  f32x4 acc2[3][4];
#pragma unroll
  for (int t = 0; t < 3; ++t)
#pragma unroll
    for (int j = 0; j < 4; ++j) acc2[t][j] = (f32x4){0.f, 0.f, 0.f, 0.f};

  // ======= mlp pair tiles: M1_nt (buf1) then slab_nt (buf0) =======
#pragma unroll
  for (int nt = 0; nt < 6; ++nt) {
    // ---- M1_nt phase ----
    __syncthreads();             // buf0 (slab_{nt-1}) reads done; Hm(LN2/mid) visible
    STAGE_S(nt, Bs[0]);          // stage slab_nt
    if (nt == 0) {
#pragma unroll
      for (int ks = 0; ks < 6; ++ks)
        fh[ks] = *(const short8*)&Hm[row_l * 192 + swz(row_l, ks * 4 + lk) * 8];
    }
    {
      const bf16* Bb = Bs[1];
      f32x4 acc1[4];
#pragma unroll
      for (int j = 0; j < 4; ++j) acc1[j] = (f32x4){0.f, 0.f, 0.f, 0.f};
#pragma unroll
      for (int ks = 0; ks < 6; ++ks) {
        short8 fb[4];
#pragma unroll
        for (int j = 0; j < 4; ++j) {
          int rn = j * 16 + lr;
          fb[j] = *(const short8*)&Bb[rn * 192 + swz(rn, ks * 4 + lk) * 8];
        }
#pragma unroll
        for (int j = 0; j < 4; ++j)
          acc1[j] = __builtin_amdgcn_mfma_f32_16x16x32_bf16(fb[j], fh[ks], acc1[j], 0, 0, 0);
      }
#pragma unroll
      for (int j = 0; j < 4; ++j) {
        int n = nt * 64 + j * 16 + lk * 4;
        float m4[4] = {0.f, 0.f, 0.f, 0.f};
        if (n < 360) {
          f32x4 bv = *(const f32x4*)&b1m[n];
#pragma unroll
          for (int q = 0; q < 4; ++q) {
            float v = acc1[j][q] + bv[q];
            float u = 0.7978845608028654f * (v + 0.044715f * v * v * v);
            m4[q] = v / (1.f + __expf(-2.f * u));
          }
        }
        int g = j * 2 + (lk >> 1);
        *(uint2v*)&Hm[row_l * 192 + swz(row_l, g) * 8 + half] = pack4(m4[0], m4[1], m4[2], m4[3]);
      }
    }
    // ---- slab_nt phase ----
    __syncthreads();             // buf1 (M1_nt) reads done; mid slab visible
    if (nt < 5) { STAGE_A(Bt1 + (size_t)(nt + 1) * 64 * 192, Bs[1]); }
    else        { STAGE_A(Btu, Bs[1]); }  // tile 15 = up
    {
      short8 fm[2];
#pragma unroll
      for (int s = 0; s < 2; ++s)
        fm[s] = *(const short8*)&Hm[row_l * 192 + swz(row_l, s * 4 + lk) * 8];
#pragma unroll
      for (int s = 0; s < 2; ++s)
#pragma unroll
        for (int t = 0; t < 3; ++t)
#pragma unroll
          for (int j = 0; j < 4; ++j) {
            int rn = t * 64 + j * 16 + lr;
            short8 fb2 = *(const short8*)&Bs[0][rn * 64 + swz(rn, s * 4 + lk) * 8];
            acc2[t][j] = __builtin_amdgcn_mfma_f32_16x16x32_bf16(fb2, fm[s], acc2[t][j], 0, 0, 0);
          }
    }
  }

  // ======= tok3 -> Hm, then up =======
  __syncthreads();  // slab_5 Hm reads + buf1 staging done
#pragma unroll
  for (int t = 0; t < 3; ++t)
#pragma unroll
    for (int j = 0; j < 4; ++j) {
      int n = t * 64 + j * 16 + lk * 4;
      float o4[4] = {0.f, 0.f, 0.f, 0.f};
      if (n < 180) {
        f32x4 bv = *(const f32x4*)&b2m[n];
#pragma unroll
        for (int q = 0; q < 4; ++q) o4[q] = acc2[t][j][q] + bv[q] + t2v[t][j][q];
      }
      int g = t * 8 + j * 2 + (lk >> 1);
      *(uint2v*)&Hm[row_l * 192 + swz(row_l, g) * 8 + half] = pack4(o4[0], o4[1], o4[2], o4[3]);
    }
  __syncthreads();

  short8 ft[6];
#pragma unroll
  for (int ks = 0; ks < 6; ++ks)
    ft[ks] = *(const short8*)&Hm[row_l * 192 + swz(row_l, ks * 4 + lk) * 8];
  f32x4 acc3[3];
#pragma unroll
  for (int j = 0; j < 3; ++j) acc3[j] = (f32x4){0.f, 0.f, 0.f, 0.f};
#pragma unroll
  for (int ks = 0; ks < 6; ++ks) {
    short8 fb[3];
#pragma unroll
    for (int j = 0; j < 3; ++j) {
      int rn = j * 16 + lr;
      fb[j] = *(const short8*)&Bs[1][rn * 192 + swz(rn, ks * 4 + lk) * 8];
    }
#pragma unroll
    for (int j = 0; j < 3; ++j)
      acc3[j] = __builtin_amdgcn_mfma_f32_16x16x32_bf16(fb[j], ft[ks], acc3[j], 0, 0, 0);
  }
#pragma unroll
  for (int j = 0; j < 3; ++j) {
    int n = j * 16 + lk * 4;
    f32x4 bv = *(const f32x4*)&bu[n];
    *(uint2v*)(up + (size_t)row_g * 48 + n) =
        pack4(acc3[j][0] + bv[0], acc3[j][1] + bv[1], acc3[j][2] + bv[2], acc3[j][3] + bv[3]);
  }
#undef STAGE_A
#undef STAGE_S
}

// ---------------- bicubic weights (jax Keys a=-0.5, half-pixel, edge renorm) ----------------
__device__ const float c_cubw[4][4] = {
    {-0.0439453125f, 0.3896484375f, 0.7275390625f, -0.0732421875f},
    {-0.0068359375f, 0.0908203125f, 0.9638671875f, -0.0478515625f},
    {-0.0478515625f, 0.9638671875f, 0.0908203125f, -0.0068359375f},
    {-0.0732421875f, 0.7275390625f, 0.3896484375f, -0.0439453125f},
};

__device__ __forceinline__ void cubw(int r, int ph, float* w, int& base) {
  base = r + ((ph < 2) ? -2 : -1);
  float sum = 0.f;
#pragma unroll
  for (int i = 0; i < 4; ++i) {
    int idx = base + i;
    float wi = (idx >= 0 && idx < 64) ? c_cubw[ph][i] : 0.f;
    w[i] = wi; sum += wi;
  }
  float inv = 1.f / sum;
#pragma unroll
  for (int i = 0; i < 4; ++i) w[i] *= inv;
}

// ---------------- blend: pixel-shuffle of up + bicubic + mask blend ----------------
__global__ __launch_bounds__(256) void k_blend(
    const bf16* __restrict__ up, const float* __restrict__ x,
    const float* __restrict__ maskp, float* __restrict__ sr) {
  int idx = blockIdx.x * 256 + threadIdx.x;
  int ch = idx >> 20;
  int rem = idx & 1048575;
  int gR = rem >> 10, gC = rem & 1023;
  int th = gR >> 8, tw = gC >> 8;
  int t = th * 4 + tw;
  int R = gR & 255, C = gC & 255;
  int r = R >> 2, a = R & 3, c = C >> 2, b = C & 3;
  float m = maskp[t];
  float outv;
  if (m > 0.5f) {
    int wi = r >> 4, u = r & 15, wj = c >> 4, v = c & 15;
    int wrow = (t * 16 + wi * 4 + wj) * 256 + u * 16 + v;
    outv = bf2f(up[(size_t)wrow * 48 + a * 12 + b * 3 + ch]);
  } else {
    float wy[4], wx[4];
    int yb, xb;
    cubw(r, a, wy, yb);
    cubw(c, b, wx, xb);
    const float* xc = x + ch * 65536;
    float neg = 0.f;
#pragma unroll
    for (int i = 0; i < 4; ++i) {
      int yi = yb + i;
      if (yi < 0 || yi > 63) continue;
      float rowsum = 0.f;
#pragma unroll
      for (int j = 0; j < 4; ++j) {
        int xj = xb + j;
        if (xj < 0 || xj > 63) continue;
        rowsum = fmaf(wx[j], xc[(th * 64 + yi) * 256 + tw * 64 + xj], rowsum);
      }
      neg = fmaf(wy[i], rowsum, neg);
    }
    outv = neg;
  }
  sr[idx] = outv;
}

// ---------------- launcher ----------------
extern "C" void kernel_launch(void* const* d_in, const int* in_sizes, int n_in,
                              void* d_out, int out_size, void* d_ws, size_t ws_size,
                              hipStream_t stream) {
  const float* x     = (const float*)d_in[0];
  const float* gu    = (const float*)d_in[1];
  const float* s1w   = (const float*)d_in[2];
  const float* s1b   = (const float*)d_in[3];
  const float* s2w   = (const float*)d_in[4];
  const float* s2b   = (const float*)d_in[5];
  const float* s3w   = (const float*)d_in[6];
  const float* s3b   = (const float*)d_in[7];
  const float* ew    = (const float*)d_in[8];
  const float* ebias = (const float*)d_in[9];
  const float* ln1g  = (const float*)d_in[10];
  const float* ln1b  = (const float*)d_in[11];
  const float* qkvw  = (const float*)d_in[12];
  const float* qkvb  = (const float*)d_in[13];
  const float* projw = (const float*)d_in[14];
  const float* projb = (const float*)d_in[15];
  const float* ln2g  = (const float*)d_in[16];
  const float* ln2b  = (const float*)d_in[17];
  const float* mlp1w = (const float*)d_in[18];
  const float* mlp1b = (const float*)d_in[19];
  const float* mlp2w = (const float*)d_in[20];
  const float* mlp2b = (const float*)d_in[21];
  const float* upw   = (const float*)d_in[22];
  const float* upb   = (const float*)d_in[23];

  float* out = (float*)d_out;
  float* sr  = out;                 // 3*1024*1024
  float* f3o = out + 3145728;       // 16*2
  float* f2o = f3o + 32;            // 16*32
  float* f1o = f2o + 512;           // 16*64

  char* ws = (char*)d_ws;
  bf16* tok  = (bf16*)(ws);                   // 65536*180 = 23,592,960 B
  bf16* ABuf = (bf16*)(ws + 23592960);        // 65536*192 = 25,165,824 B (LN1 out, then av)
  bf16* Qp   = (bf16*)(ws + 48758784);        // 65536*192
  bf16* Kp   = (bf16*)(ws + 73924608);        // 65536*192
  bf16* Vp   = (bf16*)(ws + 99090432);        // 65536*192
  float* maskp   = (float*)(ws + 124256256);  // 64 B
  bf16* Bt_qkv  = (bf16*)(ws + 124256320);    // 576*192*2 = 221,184
  bf16* Bt_proj = (bf16*)(ws + 124477504);    // 192*192*2 = 73,728
  bf16* Bt_mlp1 = (bf16*)(ws + 124551232);    // 384*192*2 = 147,456
  bf16* Bt_mlp2 = (bf16*)(ws + 124698688);    // 192*384*2 = 147,456
  bf16* Bt_up   = (bf16*)(ws + 124846144);    // 64*192*2  = 24,576
  float* biasq  = (float*)(ws + 124870720);   // 576*4 = 2,304
  bf16* up      = (bf16*)(ws + 124873088);    // 65536*48*2 = 6,291,456
  bf16* av = ABuf;  // alias: ABuf dead after k_qkv3

  k_packsel<<<1219, 256, 0, stream>>>(qkvw, projw, mlp1w, mlp2w, upw, qkvb,
                                      Bt_qkv, Bt_proj, Bt_mlp1, Bt_mlp2, Bt_up, biasq,
                                      x, gu, s1w, s1b, s2w, s2b, s3w, s3b,
                                      f1o, f2o, f3o, maskp);
  k_embed<<<16384, 256, 0, stream>>>(x, ew, ebias, ln1g, ln1b, tok, ABuf);
  k_qkv3<<<256, 1024, 0, stream>>>(ABuf, Bt_qkv, biasq, Qp, Kp, Vp);
  k_attn2<<<1536, 256, 0, stream>>>(Qp, Kp, Vp, av);
  k_post<<<256, 1024, 0, stream>>>(av, tok, Bt_proj, projb, ln2g, ln2b,
                                   Bt_mlp1, mlp1b, Bt_mlp2, mlp2b, Bt_up, upb, up);
  k_blend<<<12288, 256, 0, stream>>>(up, x, maskp, sr);
}

// Round 13
// 203.410 us; speedup vs baseline: 1.0698x; 1.0698x over previous
//
#include <hip/hip_runtime.h>
#include <hip/hip_bf16.h>
#include <cstdint>

typedef __hip_bfloat16 bf16;
typedef __attribute__((ext_vector_type(8))) short short8;
typedef __attribute__((ext_vector_type(4))) short short4v;
typedef __attribute__((ext_vector_type(4))) float f32x4;
typedef __attribute__((ext_vector_type(2))) unsigned int uint2v;

__device__ __forceinline__ float bf2f(bf16 v) { return __bfloat162float(v); }
__device__ __forceinline__ bf16  f2bf(float v) { return __float2bfloat16(v); }
__device__ __forceinline__ float rbf(short s) {
  union { uint32_t u; float f; } c; c.u = ((uint32_t)(uint16_t)s) << 16; return c.f;
}
__device__ __forceinline__ short wbf(float f) {
  bf16 h = f2bf(f); return *(short*)&h;
}
__device__ __forceinline__ uint32_t pack2(float a, float b) {
  bf16 x = f2bf(a), y = f2bf(b);
  return (uint32_t)(*(uint16_t*)&x) | ((uint32_t)(*(uint16_t*)&y) << 16);
}
__device__ __forceinline__ uint2v pack4(float a, float b, float c, float d) {
  uint2v r; r[0] = pack2(a, b); r[1] = pack2(c, d); return r;
}
// granule swizzle: XOR low-3 bits of 8-elem granule index with row&7
__device__ __forceinline__ int swz(int row, int g) { return g ^ (row & 7); }

// window-order row m -> token index (t*4096 + p)
__device__ __forceinline__ int win_to_token(int m) {
  int n = m >> 8, l = m & 255;
  int t = n >> 4, win = n & 15;
  int wi = win >> 2, wj = win & 3;
  int u = l >> 4, v = l & 15;
  return (t << 12) | ((wi * 16 + u) << 6) | (wj * 16 + v);
}

// ---------------- merged: weight packing + selector MLP ----------------
__global__ __launch_bounds__(256) void k_packsel(
    const float* __restrict__ qkvw, const float* __restrict__ projw,
    const float* __restrict__ mlp1w, const float* __restrict__ mlp2w,
    const float* __restrict__ upw, const float* __restrict__ qkvb,
    bf16* __restrict__ Bt_qkv, bf16* __restrict__ Bt_proj,
    bf16* __restrict__ Bt_mlp1, bf16* __restrict__ Bt_mlp2,
    bf16* __restrict__ Bt_up, float* __restrict__ biasq,
    const float* __restrict__ x, const float* __restrict__ gu,
    const float* __restrict__ s1w, const float* __restrict__ s1b,
    const float* __restrict__ s2w, const float* __restrict__ s2b,
    const float* __restrict__ s3w, const float* __restrict__ s3b,
    float* __restrict__ f1o, float* __restrict__ f2o, float* __restrict__ f3o,
    float* __restrict__ maskp) {
  if (blockIdx.x < 1203) {
    int idx = blockIdx.x * 256 + threadIdx.x;
    const int e0 = 576 * 192, e1 = e0 + 192 * 192, e2 = e1 + 384 * 192,
              e3 = e2 + 192 * 384, e4 = e3 + 64 * 192, e5 = e4 + 576;
    if (idx < e0) {
      int np = idx / 192, k = idx % 192;
      int buf = np / 192, colp = np % 192;
      int hd = colp >> 5, dd = colp & 31;
      float v = 0.f;
      if (dd < 30 && k < 180) v = qkvw[(size_t)k * 540 + buf * 180 + hd * 30 + dd];
      Bt_qkv[idx] = f2bf(v);
    } else if (idx < e1) {
      int off = idx - e0; int n = off / 192, kp = off % 192;
      int hd = kp >> 5, dd = kp & 31;
      float v = (dd < 30 && n < 180) ? projw[(size_t)(hd * 30 + dd) * 180 + n] : 0.f;
      Bt_proj[off] = f2bf(v);
    } else if (idx < e2) {
      int off = idx - e1; int n = off / 192, k = off % 192;
      Bt_mlp1[off] = f2bf((k < 180 && n < 360) ? mlp1w[(size_t)k * 360 + n] : 0.f);
    } else if (idx < e3) {
      int off = idx - e2; int n = off / 384, k = off % 384;
      Bt_mlp2[off] = f2bf((k < 360 && n < 180) ? mlp2w[(size_t)k * 180 + n] : 0.f);
    } else if (idx < e4) {
      int off = idx - e3; int n = off / 192, k = off % 192;
      Bt_up[off] = f2bf((k < 180 && n < 48) ? upw[(size_t)k * 48 + n] : 0.f);
    } else if (idx < e5) {
      int np = idx - e4;
      int buf = np / 192, colp = np % 192;
      int hd = colp >> 5, dd = colp & 31;
      biasq[np] = (dd < 30) ? qkvb[buf * 180 + hd * 30 + dd] : 0.f;
    }
    return;
  }
  // ---- selector (blocks 1203..1218), 256 threads ----
  int t = blockIdx.x - 1203;
  int tid = threadIdx.x;
  int th = t >> 2, tw = t & 3;
  __shared__ float pooled[192];
  __shared__ float red[256];
  __shared__ float f1s[64], f2s[32], f3s[2];
  if (tid < 192) {
    int ch = tid % 3, j = (tid / 3) & 7, i = tid / 24;
    const float* xp = x + ch * 65536 + (th * 64 + i * 8) * 256 + (tw * 64 + j * 8);
    float s = 0.f;
#pragma unroll
    for (int a = 0; a < 8; ++a)
#pragma unroll
      for (int b = 0; b < 8; ++b) s += xp[a * 256 + b];
    pooled[tid] = s * (1.0f / 64.0f);
  }
  __syncthreads();
  {
    int o = tid & 63, part = tid >> 6;
    float s = 0.f;
    for (int k = part * 48; k < part * 48 + 48; ++k) s = fmaf(pooled[k], s1w[k * 64 + o], s);
    red[tid] = s;
  }
  __syncthreads();
  if (tid < 64) {
    float v = red[tid] + red[tid + 64] + red[tid + 128] + red[tid + 192] + s1b[tid];
    f1o[t * 64 + tid] = v;
    f1s[tid] = fmaxf(v, 0.f);
  }
  __syncthreads();
  {
    int o = tid & 31, part = tid >> 5;
    float s = 0.f;
    for (int k = part * 8; k < part * 8 + 8; ++k) s = fmaf(f1s[k], s2w[k * 32 + o], s);
    red[tid] = s;
  }
  __syncthreads();
  if (tid < 32) {
    float v = s2b[tid];
#pragma unroll
    for (int p = 0; p < 8; ++p) v += red[tid + p * 32];
    f2o[t * 32 + tid] = v;
    f2s[tid] = fmaxf(v, 0.f);
  }
  __syncthreads();
  if (tid < 2) {
    float s = s3b[tid];
    for (int k = 0; k < 32; ++k) s = fmaf(f2s[k], s3w[k * 2 + tid], s);
    f3o[t * 2 + tid] = s;
    f3s[tid] = s;
  }
  __syncthreads();
  if (tid == 0) {
    float g0 = -logf(-logf(gu[t * 2 + 0] + 1e-10f) + 1e-10f);
    float g1 = -logf(-logf(gu[t * 2 + 1] + 1e-10f) + 1e-10f);
    maskp[t] = (f3s[1] + g1 > f3s[0] + g0) ? 1.0f : 0.0f;
  }
}

// ---------------- embed (3->180) + LN1 applied, outputs window-major ----------------
__global__ __launch_bounds__(256) void k_embed(
    const float* __restrict__ x, const float* __restrict__ ew,
    const float* __restrict__ eb, const float* __restrict__ g1,
    const float* __restrict__ b1, bf16* __restrict__ tok,
    bf16* __restrict__ Aq) {
  int wrow = blockIdx.x * 4 + (threadIdx.x >> 6);
  int lane = threadIdx.x & 63;
  int token = win_to_token(wrow);
  int t = token >> 12, p = token & 4095;
  int r = p >> 6, c = p & 63;
  int gh = (t >> 2) * 64 + r, gw = (t & 3) * 64 + c;
  float x0 = x[gh * 256 + gw];
  float x1 = x[65536 + gh * 256 + gw];
  float x2 = x[131072 + gh * 256 + gw];
  float v[3];
  float s = 0.f, s2 = 0.f;
#pragma unroll
  for (int i = 0; i < 3; ++i) {
    int e = lane + i * 64;
    float vv = 0.f;
    if (e < 180) {
      vv = eb[e];
      vv = fmaf(x0, ew[e], vv);
      vv = fmaf(x1, ew[180 + e], vv);
      vv = fmaf(x2, ew[360 + e], vv);
      tok[(size_t)wrow * 180 + e] = f2bf(vv);
      s += vv; s2 = fmaf(vv, vv, s2);
    }
    v[i] = vv;
  }
#pragma unroll
  for (int off = 32; off; off >>= 1) { s += __shfl_xor(s, off); s2 += __shfl_xor(s2, off); }
  float mu = s * (1.f / 180.f);
  float rs = rsqrtf(s2 * (1.f / 180.f) - mu * mu + 1e-5f);
#pragma unroll
  for (int i = 0; i < 3; ++i) {
    int e = lane + i * 64;
    if (e < 192) {
      float a = (e < 180) ? ((v[i] - mu) * rs * g1[e] + b1[e]) : 0.f;
      Aq[(size_t)wrow * 192 + e] = f2bf(a);
    }
  }
}

// ---------------- qkv GEMM: 1024 thr / 256 rows / grid 256; dbuf LDS B ------
__global__ __launch_bounds__(1024, 4) void k_qkv3(
    const bf16* __restrict__ A, const bf16* __restrict__ Bt,
    const float* __restrict__ biasq, bf16* __restrict__ Qp,
    bf16* __restrict__ Kp, bf16* __restrict__ Vp) {
  __shared__ bf16 Bs[2][64 * 192];
  const int tid = threadIdx.x;
  const int w = tid >> 6, l = tid & 63;
  const int lr = l & 15, lk = l >> 4;
  const int row = blockIdx.x * 256 + w * 16 + lr;

  short8 fa[6];
  {
    const bf16* Ab = A + (size_t)row * 192 + lk * 8;
#pragma unroll
    for (int ks = 0; ks < 6; ++ks) fa[ks] = *(const short8*)(Ab + ks * 32);
  }

  for (int c = tid; c < 1536; c += 1024) {
    int n = c / 24, g = c % 24;
    *(short8*)&Bs[0][n * 192 + swz(n, g) * 8] = *(const short8*)(Bt + (size_t)n * 192 + g * 8);
  }

  for (int nt = 0; nt < 9; ++nt) {
    __syncthreads();
    if (nt < 8) {
      const bf16* src = Bt + (size_t)(nt + 1) * 64 * 192;
      bf16* dstb = Bs[(nt + 1) & 1];
      for (int c = tid; c < 1536; c += 1024) {
        int n = c / 24, g = c % 24;
        *(short8*)&dstb[n * 192 + swz(n, g) * 8] = *(const short8*)(src + (size_t)n * 192 + g * 8);
      }
    }
    const bf16* Bb = Bs[nt & 1];
    f32x4 acc[4];
#pragma unroll
    for (int j = 0; j < 4; ++j) acc[j] = (f32x4){0.f, 0.f, 0.f, 0.f};
#pragma unroll
    for (int ks = 0; ks < 6; ++ks) {
      short8 fb[4];
#pragma unroll
      for (int j = 0; j < 4; ++j) {
        int rn = j * 16 + lr;
        fb[j] = *(const short8*)&Bb[rn * 192 + swz(rn, ks * 4 + lk) * 8];
      }
#pragma unroll
      for (int j = 0; j < 4; ++j)
        acc[j] = __builtin_amdgcn_mfma_f32_16x16x32_bf16(fb[j], fa[ks], acc[j], 0, 0, 0);
    }
    bf16* dst = (nt < 3) ? Qp : (nt < 6) ? Kp : Vp;
    int c0 = (nt % 3) * 64;
#pragma unroll
    for (int j = 0; j < 4; ++j) {
      int np = nt * 64 + j * 16 + lk * 4;
      f32x4 bv = *(const f32x4*)&biasq[np];
      *(uint2v*)(dst + (size_t)row * 192 + c0 + j * 16 + lk * 4) =
          pack4(acc[j][0] + bv[0], acc[j][1] + bv[1], acc[j][2] + bv[2], acc[j][3] + bv[3]);
    }
  }
}

// ---------------- MFMA attention: block = (window, head), swapped PV ----------------
__global__ __launch_bounds__(256) void k_attn2(
    const bf16* __restrict__ Qp, const bf16* __restrict__ Kp,
    const bf16* __restrict__ Vp, bf16* __restrict__ av) {
  const int blk = blockIdx.x;
  const int win = blk / 6, hd = blk % 6;
  const int tid = threadIdx.x;
  const int w = tid >> 6, l = tid & 63;
  const int lr = l & 15, lk = l >> 4;
  const float scale = 0.18257418583505536f;  // 1/sqrt(30)

  __shared__ bf16 Ks[256][40];
  __shared__ bf16 Vs[32][264];
  __shared__ bf16 Ps[4][16][264];

  {  // stage K rows
    const bf16* src = Kp + (size_t)(win * 256 + tid) * 192 + hd * 32;
#pragma unroll
    for (int c = 0; c < 4; ++c)
      *(short8*)&Ks[tid][c * 8] = *(const short8*)(src + c * 8);
  }
  {  // stage V rows -> transposed Vs[d][key]
    const bf16* src = Vp + (size_t)(win * 256 + tid) * 192 + hd * 32;
    short8 vv[4];
#pragma unroll
    for (int c = 0; c < 4; ++c) vv[c] = *(const short8*)(src + c * 8);
#pragma unroll
    for (int c = 0; c < 4; ++c)
#pragma unroll
      for (int e = 0; e < 8; ++e)
        *(short*)&Vs[c * 8 + e][tid] = vv[c][e];
  }
  __syncthreads();

  for (int qt = 0; qt < 4; ++qt) {
    const int qbase = qt * 64 + w * 16;
    short8 fq = *(const short8*)(Qp + (size_t)(win * 256 + qbase + lr) * 192 + hd * 32 + lk * 8);
    f32x4 accS[16];
#pragma unroll
    for (int kt = 0; kt < 16; ++kt) {
      short8 fk = *(const short8*)(&Ks[kt * 16 + lr][lk * 8]);
      accS[kt] = __builtin_amdgcn_mfma_f32_16x16x32_bf16(
          fk, fq, (f32x4){0.f, 0.f, 0.f, 0.f}, 0, 0, 0);
    }
    float mraw = -1e30f;
#pragma unroll
    for (int kt = 0; kt < 16; ++kt)
#pragma unroll
      for (int r = 0; r < 4; ++r) mraw = fmaxf(mraw, accS[kt][r]);
    mraw = fmaxf(mraw, __shfl_xor(mraw, 16));
    mraw = fmaxf(mraw, __shfl_xor(mraw, 32));
    const float mc = mraw * scale;
    float lsum = 0.f;
#pragma unroll
    for (int kt = 0; kt < 16; ++kt) {
      float p0 = __expf(fmaf(accS[kt][0], scale, -mc));
      float p1 = __expf(fmaf(accS[kt][1], scale, -mc));
      float p2 = __expf(fmaf(accS[kt][2], scale, -mc));
      float p3 = __expf(fmaf(accS[kt][3], scale, -mc));
      lsum += (p0 + p1) + (p2 + p3);
      *(uint32_t*)&Ps[w][lr][kt * 16 + lk * 4]     = pack2(p0, p1);
      *(uint32_t*)&Ps[w][lr][kt * 16 + lk * 4 + 2] = pack2(p2, p3);
    }
    lsum += __shfl_xor(lsum, 16);
    lsum += __shfl_xor(lsum, 32);
    __syncthreads();
    f32x4 accO0 = (f32x4){0.f, 0.f, 0.f, 0.f};
    f32x4 accO1 = (f32x4){0.f, 0.f, 0.f, 0.f};
#pragma unroll
    for (int ks = 0; ks < 8; ++ks) {
      short8 fp  = *(const short8*)(&Ps[w][lr][ks * 32 + lk * 8]);
      short8 fv0 = *(const short8*)(&Vs[lr][ks * 32 + lk * 8]);
      short8 fv1 = *(const short8*)(&Vs[16 + lr][ks * 32 + lk * 8]);
      accO0 = __builtin_amdgcn_mfma_f32_16x16x32_bf16(fv0, fp, accO0, 0, 0, 0);
      accO1 = __builtin_amdgcn_mfma_f32_16x16x32_bf16(fv1, fp, accO1, 0, 0, 0);
    }
    float invl = 1.f / lsum;
    bf16* avrow = av + (size_t)(win * 256 + qbase + lr) * 192 + hd * 32;
    *(uint2v*)(avrow + lk * 4) =
        pack4(accO0[0] * invl, accO0[1] * invl, accO0[2] * invl, accO0[3] * invl);
    *(uint2v*)(avrow + 16 + lk * 4) =
        pack4(accO1[0] * invl, accO1[1] * invl, accO1[2] * invl, accO1[3] * invl);
    __syncthreads();
  }
}

// ---------------- fused post-attn, 1024 thr / 256 rows / grid 256 ----
// t2 kept as packed bf16 (24 VGPR) to stay under the 128-VGPR / 4-waves-per-EU cap.
__global__ __launch_bounds__(1024, 4) void k_post(
    const bf16* __restrict__ av, const bf16* __restrict__ tok,
    const bf16* __restrict__ Btp, const float* __restrict__ pb,
    const float* __restrict__ g2, const float* __restrict__ b2,
    const bf16* __restrict__ Bt1, const float* __restrict__ b1m,
    const bf16* __restrict__ Bt2, const float* __restrict__ b2m,
    const bf16* __restrict__ Btu, const float* __restrict__ bu,
    bf16* __restrict__ up) {
  __shared__ bf16 Bs[2][64 * 192];   // 49,152 B
  __shared__ bf16 Hm[256 * 192];     // 98,304 B
  const int tid = threadIdx.x;
  const int w = tid >> 6, l = tid & 63;
  const int lr = l & 15, lk = l >> 4;
  const int row_l = w * 16 + lr;
  const int row_g = blockIdx.x * 256 + row_l;
  const int half = (lk & 1) * 4;

#define STAGE_A(srcp, dstb)                                               \
  {                                                                       \
    const bf16* _s = (srcp);                                              \
    bf16* _d = (dstb);                                                    \
    for (int c = tid; c < 1536; c += 1024) {                              \
      int n = c / 24, g = c % 24;                                         \
      *(short8*)&_d[n * 192 + swz(n, g) * 8] =                            \
          *(const short8*)(_s + (size_t)n * 192 + g * 8);                 \
    }                                                                     \
  }
#define STAGE_S(ntv, dstb)                                                \
  {                                                                       \
    bf16* _d = (dstb);                                                    \
    for (int c = tid; c < 1536; c += 1024) {                              \
      int n = c / 8, g = c % 8;                                           \
      *(short8*)&_d[n * 64 + swz(n, g) * 8] =                             \
          *(const short8*)(Bt2 + (size_t)n * 384 + (ntv) * 64 + g * 8);   \
    }                                                                     \
  }

  // av A-frags
  short8 fa[6];
  {
    const bf16* ab = av + (size_t)row_g * 192 + lk * 8;
#pragma unroll
    for (int ks = 0; ks < 6; ++ks) fa[ks] = *(const short8*)(ab + ks * 32);
  }

  short4v t2p[3][4];   // proj+residual, packed bf16 (2 VGPR each)
  float sA = 0.f, s2A = 0.f;  // LN2 partial stats (f32, pre-rounding)

  // ---- prologue: stage proj0 ----
  STAGE_A(Btp, Bs[0]);

  // ======= proj tiles (t=0,1,2) =======
#pragma unroll
  for (int nt = 0; nt < 3; ++nt) {
    __syncthreads();
    if (nt < 2) { STAGE_A(Btp + (size_t)(nt + 1) * 64 * 192, Bs[(nt + 1) & 1]); }
    else        { STAGE_A(Bt1, Bs[1]); }  // tile 3 = mlp1_0
    const bf16* Bb = Bs[nt & 1];
    f32x4 acc[4];
#pragma unroll
    for (int j = 0; j < 4; ++j) acc[j] = (f32x4){0.f, 0.f, 0.f, 0.f};
#pragma unroll
    for (int ks = 0; ks < 6; ++ks) {
      short8 fb[4];
#pragma unroll
      for (int j = 0; j < 4; ++j) {
        int rn = j * 16 + lr;
        fb[j] = *(const short8*)&Bb[rn * 192 + swz(rn, ks * 4 + lk) * 8];
      }
#pragma unroll
      for (int j = 0; j < 4; ++j)
        acc[j] = __builtin_amdgcn_mfma_f32_16x16x32_bf16(fb[j], fa[ks], acc[j], 0, 0, 0);
    }
#pragma unroll
    for (int j = 0; j < 4; ++j) {
      int n = nt * 64 + j * 16 + lk * 4;
      if (n < 180) {
        f32x4 bv = *(const f32x4*)&pb[n];
        short4v tv = *(const short4v*)(tok + (size_t)row_g * 180 + n);
#pragma unroll
        for (int q = 0; q < 4; ++q) {
          float v = acc[j][q] + bv[q] + rbf(tv[q]);
          sA += v; s2A = fmaf(v, v, s2A);
          t2p[nt][j][q] = wbf(v);
        }
      } else {
#pragma unroll
        for (int q = 0; q < 4; ++q) t2p[nt][j][q] = 0;
      }
    }
  }

  // ======= LN2 stats (f32 partials), H2 -> Hm from bf16 t2 =======
  {
    sA += __shfl_xor(sA, 16);  sA += __shfl_xor(sA, 32);
    s2A += __shfl_xor(s2A, 16); s2A += __shfl_xor(s2A, 32);
    float mu = sA * (1.f / 180.f);
    float rs = rsqrtf(s2A * (1.f / 180.f) - mu * mu + 1e-5f);
#pragma unroll
    for (int nt = 0; nt < 3; ++nt)
#pragma unroll
      for (int j = 0; j < 4; ++j) {
        int n = nt * 64 + j * 16 + lk * 4;
        float h[4] = {0.f, 0.f, 0.f, 0.f};
        if (n < 180) {
          f32x4 gv = *(const f32x4*)&g2[n];
          f32x4 bv = *(const f32x4*)&b2[n];
#pragma unroll
          for (int q = 0; q < 4; ++q)
            h[q] = (rbf(t2p[nt][j][q]) - mu) * rs * gv[q] + bv[q];
        }
        int g = nt * 8 + j * 2 + (lk >> 1);
        *(uint2v*)&Hm[row_l * 192 + swz(row_l, g) * 8 + half] = pack4(h[0], h[1], h[2], h[3]);
      }
  }

  short8 fh[6];
  f32x4 acc2[3][4];
#pragma unroll
  for (int t = 0; t < 3; ++t)
#pragma unroll
    for (int j = 0; j < 4; ++j) acc2[t][j] = (f32x4){0.f, 0.f, 0.f, 0.f};

  // ======= mlp pair tiles: M1_nt (buf1) then slab_nt (buf0) =======
#pragma unroll
  for (int nt = 0; nt < 6; ++nt) {
    // ---- M1_nt phase ----
    __syncthreads();             // buf0 (slab_{nt-1}) reads done; Hm(LN2/mid) visible
    STAGE_S(nt, Bs[0]);          // stage slab_nt
    if (nt == 0) {
#pragma unroll
      for (int ks = 0; ks < 6; ++ks)
        fh[ks] = *(const short8*)&Hm[row_l * 192 + swz(row_l, ks * 4 + lk) * 8];
    }
    {
      const bf16* Bb = Bs[1];
      f32x4 acc1[4];
#pragma unroll
      for (int j = 0; j < 4; ++j) acc1[j] = (f32x4){0.f, 0.f, 0.f, 0.f};
#pragma unroll
      for (int ks = 0; ks < 6; ++ks) {
        short8 fb[4];
#pragma unroll
        for (int j = 0; j < 4; ++j) {
          int rn = j * 16 + lr;
          fb[j] = *(const short8*)&Bb[rn * 192 + swz(rn, ks * 4 + lk) * 8];
        }
#pragma unroll
        for (int j = 0; j < 4; ++j)
          acc1[j] = __builtin_amdgcn_mfma_f32_16x16x32_bf16(fb[j], fh[ks], acc1[j], 0, 0, 0);
      }
#pragma unroll
      for (int j = 0; j < 4; ++j) {
        int n = nt * 64 + j * 16 + lk * 4;
        float m4[4] = {0.f, 0.f, 0.f, 0.f};
        if (n < 360) {
          f32x4 bv = *(const f32x4*)&b1m[n];
#pragma unroll
          for (int q = 0; q < 4; ++q) {
            float v = acc1[j][q] + bv[q];
            float u = 0.7978845608028654f * (v + 0.044715f * v * v * v);
            m4[q] = v / (1.f + __expf(-2.f * u));
          }
        }
        int g = j * 2 + (lk >> 1);
        *(uint2v*)&Hm[row_l * 192 + swz(row_l, g) * 8 + half] = pack4(m4[0], m4[1], m4[2], m4[3]);
      }
    }
    // ---- slab_nt phase ----
    __syncthreads();             // buf1 (M1_nt) reads done; mid slab visible
    if (nt < 5) { STAGE_A(Bt1 + (size_t)(nt + 1) * 64 * 192, Bs[1]); }
    else        { STAGE_A(Btu, Bs[1]); }  // tile 15 = up
    {
      short8 fm[2];
#pragma unroll
      for (int s = 0; s < 2; ++s)
        fm[s] = *(const short8*)&Hm[row_l * 192 + swz(row_l, s * 4 + lk) * 8];
#pragma unroll
      for (int s = 0; s < 2; ++s)
#pragma unroll
        for (int t = 0; t < 3; ++t)
#pragma unroll
          for (int j = 0; j < 4; ++j) {
            int rn = t * 64 + j * 16 + lr;
            short8 fb2 = *(const short8*)&Bs[0][rn * 64 + swz(rn, s * 4 + lk) * 8];
            acc2[t][j] = __builtin_amdgcn_mfma_f32_16x16x32_bf16(fb2, fm[s], acc2[t][j], 0, 0, 0);
          }
    }
  }

  // ======= tok3 -> Hm, then up =======
  __syncthreads();  // slab_5 Hm reads + buf1 staging done
#pragma unroll
  for (int t = 0; t < 3; ++t)
#pragma unroll
    for (int j = 0; j < 4; ++j) {
      int n = t * 64 + j * 16 + lk * 4;
      float o4[4] = {0.f, 0.f, 0.f, 0.f};
      if (n < 180) {
        f32x4 bv = *(const f32x4*)&b2m[n];
#pragma unroll
        for (int q = 0; q < 4; ++q) o4[q] = acc2[t][j][q] + bv[q] + rbf(t2p[t][j][q]);
      }
      int g = t * 8 + j * 2 + (lk >> 1);
      *(uint2v*)&Hm[row_l * 192 + swz(row_l, g) * 8 + half] = pack4(o4[0], o4[1], o4[2], o4[3]);
    }
  __syncthreads();

  short8 ft[6];
#pragma unroll
  for (int ks = 0; ks < 6; ++ks)
    ft[ks] = *(const short8*)&Hm[row_l * 192 + swz(row_l, ks * 4 + lk) * 8];
  f32x4 acc3[3];
#pragma unroll
  for (int j = 0; j < 3; ++j) acc3[j] = (f32x4){0.f, 0.f, 0.f, 0.f};
#pragma unroll
  for (int ks = 0; ks < 6; ++ks) {
    short8 fb[3];
#pragma unroll
    for (int j = 0; j < 3; ++j) {
      int rn = j * 16 + lr;
      fb[j] = *(const short8*)&Bs[1][rn * 192 + swz(rn, ks * 4 + lk) * 8];
    }
#pragma unroll
    for (int j = 0; j < 3; ++j)
      acc3[j] = __builtin_amdgcn_mfma_f32_16x16x32_bf16(fb[j], ft[ks], acc3[j], 0, 0, 0);
  }
#pragma unroll
  for (int j = 0; j < 3; ++j) {
    int n = j * 16 + lk * 4;
    f32x4 bv = *(const f32x4*)&bu[n];
    *(uint2v*)(up + (size_t)row_g * 48 + n) =
        pack4(acc3[j][0] + bv[0], acc3[j][1] + bv[1], acc3[j][2] + bv[2], acc3[j][3] + bv[3]);
  }
#undef STAGE_A
#undef STAGE_S
}

// ---------------- bicubic weights (jax Keys a=-0.5, half-pixel, edge renorm) ----------------
__device__ const float c_cubw[4][4] = {
    {-0.0439453125f, 0.3896484375f, 0.7275390625f, -0.0732421875f},
    {-0.0068359375f, 0.0908203125f, 0.9638671875f, -0.0478515625f},
    {-0.0478515625f, 0.9638671875f, 0.0908203125f, -0.0068359375f},
    {-0.0732421875f, 0.7275390625f, 0.3896484375f, -0.0439453125f},
};

__device__ __forceinline__ void cubw(int r, int ph, float* w, int& base) {
  base = r + ((ph < 2) ? -2 : -1);
  float sum = 0.f;
#pragma unroll
  for (int i = 0; i < 4; ++i) {
    int idx = base + i;
    float wi = (idx >= 0 && idx < 64) ? c_cubw[ph][i] : 0.f;
    w[i] = wi; sum += wi;
  }
  float inv = 1.f / sum;
#pragma unroll
  for (int i = 0; i < 4; ++i) w[i] *= inv;
}

// ---------------- blend: pixel-shuffle of up + bicubic + mask blend ----------------
__global__ __launch_bounds__(256) void k_blend(
    const bf16* __restrict__ up, const float* __restrict__ x,
    const float* __restrict__ maskp, float* __restrict__ sr) {
  int idx = blockIdx.x * 256 + threadIdx.x;
  int ch = idx >> 20;
  int rem = idx & 1048575;
  int gR = rem >> 10, gC = rem & 1023;
  int th = gR >> 8, tw = gC >> 8;
  int t = th * 4 + tw;
  int R = gR & 255, C = gC & 255;
  int r = R >> 2, a = R & 3, c = C >> 2, b = C & 3;
  float m = maskp[t];
  float outv;
  if (m > 0.5f) {
    int wi = r >> 4, u = r & 15, wj = c >> 4, v = c & 15;
    int wrow = (t * 16 + wi * 4 + wj) * 256 + u * 16 + v;
    outv = bf2f(up[(size_t)wrow * 48 + a * 12 + b * 3 + ch]);
  } else {
    float wy[4], wx[4];
    int yb, xb;
    cubw(r, a, wy, yb);
    cubw(c, b, wx, xb);
    const float* xc = x + ch * 65536;
    float neg = 0.f;
#pragma unroll
    for (int i = 0; i < 4; ++i) {
      int yi = yb + i;
      if (yi < 0 || yi > 63) continue;
      float rowsum = 0.f;
#pragma unroll
      for (int j = 0; j < 4; ++j) {
        int xj = xb + j;
        if (xj < 0 || xj > 63) continue;
        rowsum = fmaf(wx[j], xc[(th * 64 + yi) * 256 + tw * 64 + xj], rowsum);
      }
      neg = fmaf(wy[i], rowsum, neg);
    }
    outv = neg;
  }
  sr[idx] = outv;
}

// ---------------- launcher ----------------
extern "C" void kernel_launch(void* const* d_in, const int* in_sizes, int n_in,
                              void* d_out, int out_size, void* d_ws, size_t ws_size,
                              hipStream_t stream) {
  const float* x     = (const float*)d_in[0];
  const float* gu    = (const float*)d_in[1];
  const float* s1w   = (const float*)d_in[2];
  const float* s1b   = (const float*)d_in[3];
  const float* s2w   = (const float*)d_in[4];
  const float* s2b   = (const float*)d_in[5];
  const float* s3w   = (const float*)d_in[6];
  const float* s3b   = (const float*)d_in[7];
  const float* ew    = (const float*)d_in[8];
  const float* ebias = (const float*)d_in[9];
  const float* ln1g  = (const float*)d_in[10];
  const float* ln1b  = (const float*)d_in[11];
  const float* qkvw  = (const float*)d_in[12];
  const float* qkvb  = (const float*)d_in[13];
  const float* projw = (const float*)d_in[14];
  const float* projb = (const float*)d_in[15];
  const float* ln2g  = (const float*)d_in[16];
  const float* ln2b  = (const float*)d_in[17];
  const float* mlp1w = (const float*)d_in[18];
  const float* mlp1b = (const float*)d_in[19];
  const float* mlp2w = (const float*)d_in[20];
  const float* mlp2b = (const float*)d_in[21];
  const float* upw   = (const float*)d_in[22];
  const float* upb   = (const float*)d_in[23];

  float* out = (float*)d_out;
  float* sr  = out;                 // 3*1024*1024
  float* f3o = out + 3145728;       // 16*2
  float* f2o = f3o + 32;            // 16*32
  float* f1o = f2o + 512;           // 16*64

  char* ws = (char*)d_ws;
  bf16* tok  = (bf16*)(ws);                   // 65536*180 = 23,592,960 B
  bf16* ABuf = (bf16*)(ws + 23592960);        // 65536*192 = 25,165,824 B (LN1 out, then av)
  bf16* Qp   = (bf16*)(ws + 48758784);        // 65536*192
  bf16* Kp   = (bf16*)(ws + 73924608);        // 65536*192
  bf16* Vp   = (bf16*)(ws + 99090432);        // 65536*192
  float* maskp   = (float*)(ws + 124256256);  // 64 B
  bf16* Bt_qkv  = (bf16*)(ws + 124256320);    // 576*192*2 = 221,184
  bf16* Bt_proj = (bf16*)(ws + 124477504);    // 192*192*2 = 73,728
  bf16* Bt_mlp1 = (bf16*)(ws + 124551232);    // 384*192*2 = 147,456
  bf16* Bt_mlp2 = (bf16*)(ws + 124698688);    // 192*384*2 = 147,456
  bf16* Bt_up   = (bf16*)(ws + 124846144);    // 64*192*2  = 24,576
  float* biasq  = (float*)(ws + 124870720);   // 576*4 = 2,304
  bf16* up      = (bf16*)(ws + 124873088);    // 65536*48*2 = 6,291,456
  bf16* av = ABuf;  // alias: ABuf dead after k_qkv3

  k_packsel<<<1219, 256, 0, stream>>>(qkvw, projw, mlp1w, mlp2w, upw, qkvb,
                                      Bt_qkv, Bt_proj, Bt_mlp1, Bt_mlp2, Bt_up, biasq,
                                      x, gu, s1w, s1b, s2w, s2b, s3w, s3b,
                                      f1o, f2o, f3o, maskp);
  k_embed<<<16384, 256, 0, stream>>>(x, ew, ebias, ln1g, ln1b, tok, ABuf);
  k_qkv3<<<256, 1024, 0, stream>>>(ABuf, Bt_qkv, biasq, Qp, Kp, Vp);
  k_attn2<<<1536, 256, 0, stream>>>(Qp, Kp, Vp, av);
  k_post<<<256, 1024, 0, stream>>>(av, tok, Bt_proj, projb, ln2g, ln2b,
                                   Bt_mlp1, mlp1b, Bt_mlp2, mlp2b, Bt_up, upb, up);
  k_blend<<<12288, 256, 0, stream>>>(up, x, maskp, sr);
}